// Round 4
// baseline (41.406 us; speedup 1.0000x reference)
//
#include <hip/hip_runtime.h>

#define L 24
#define W 24
#define H 24
#define C 32
#define K 5
#define P 2
#define ZP (H + 2*P)          // 28  padded z-extent
#define YB 4                  // y rows per block
#define YW (YB + 2*P)         // 8   padded y-window
#define SLAB (K*YW*ZP)        // 5*8*28 = 1120 floats
#define JOUT (K*K*K)          // 125
#define ROWOUT (H*JOUT)       // 3000 floats per (c,x,y)
#define ROWV4 (ROWOUT/4)      // 750 float4 per row

typedef float f32x4 __attribute__((ext_vector_type(4)));

__global__ __launch_bounds__(256) void selfcorr_kernel(const float* __restrict__ q,
                                                       float* __restrict__ out) {
    __shared__ float s_nb[SLAB];   // [xx][yy][zz] zero-padded slab
    __shared__ int   s_t[JOUT];    // t[j] = (k0*YW + k1)*ZP + k2

    const int blk = blockIdx.x;               // (c*L + x)*(W/YB) + yb
    const int yb = blk % (W / YB);
    const int cx = blk / (W / YB);
    const int x  = cx % L;
    const int c  = cx / L;
    const int y0 = yb * YB;
    const int tid = threadIdx.x;

    // Stage zero-padded slab: s_nb[(xx*YW+yy)*ZP+zz] = q[c, x+xx-2, y0+yy-2, zz-2]
    for (int i = tid; i < SLAB; i += 256) {
        int xx = i / (YW * ZP);
        int r  = i - xx * (YW * ZP);
        int yy = r / ZP;
        int zz = r - yy * ZP;
        int gx = x + xx - P;
        int gy = y0 + yy - P;
        int gz = zz - P;
        float v = 0.0f;
        if ((unsigned)gx < (unsigned)L && (unsigned)gy < (unsigned)W && (unsigned)gz < (unsigned)H)
            v = q[((c * L + gx) * W + gy) * H + gz];
        s_nb[i] = v;
    }
    if (tid < JOUT) {
        int k0 = tid / 25;
        int r  = tid - k0 * 25;
        int k1 = r / 5;
        int k2 = r - k1 * 5;
        s_t[tid] = (k0 * YW + k1) * ZP + k2;
    }
    __syncthreads();

    float* outp = out + (size_t)((c * L + x) * W + y0) * ROWOUT;
    const int C0 = (P * YW + P) * ZP + P;   // (2*8+2)*28+2 = 506

    #pragma unroll
    for (int yl = 0; yl < YB; ++yl) {
        const int o0 = yl * ZP;
        float* rowp = outp + yl * ROWOUT;
        #pragma unroll
        for (int i = 0; i < 3; ++i) {
            int e4 = i * 256 + tid;
            if (e4 < ROWV4) {
                int e = e4 * 4;
                f32x4 v;
                #pragma unroll
                for (int u = 0; u < 4; ++u) {
                    int ee = e + u;
                    int z = ee / JOUT;
                    int j = ee - z * JOUT;
                    float p = s_nb[C0 + o0 + z] * s_nb[s_t[j] + o0 + z];
                    v[u] = fmaxf(p, 0.0f);
                }
                *reinterpret_cast<f32x4*>(rowp + e) = v;
            }
        }
    }
}

extern "C" void kernel_launch(void* const* d_in, const int* in_sizes, int n_in,
                              void* d_out, int out_size, void* d_ws, size_t ws_size,
                              hipStream_t stream) {
    const float* q = (const float*)d_in[0];
    float* out = (float*)d_out;
    const int nblk = C * L * (W / YB);   // 4608
    selfcorr_kernel<<<nblk, 256, 0, stream>>>(q, out);
}

// Round 5
// 40.006 us; speedup vs baseline: 1.0350x; 1.0350x over previous
//
#include <hip/hip_runtime.h>

#define L 24
#define W 24
#define H 24
#define C 32
#define K 5
#define P 2
#define ZP (H + 2*P)        // 28  padded z-extent
#define NBSZ (K*K*ZP)       // 700 floats per block slab
#define JOUT (K*K*K)        // 125
#define PER_BLK (H*JOUT)    // 3000 output floats per (c,x,y)
#define NV4 (PER_BLK/4)     // 750 float4 per block
#define CENTER ((P*K + P)*ZP + P)   // 338

typedef float f32x4 __attribute__((ext_vector_type(4)));

__global__ __launch_bounds__(256) void selfcorr_kernel(const float* __restrict__ q,
                                                       float* __restrict__ out) {
    __shared__ float s_nb[NBSZ];   // [kk][zz], kk = k0*5+k1, zero-padded

    const int blk = blockIdx.x;            // (c*24 + x)*24 + y
    const int y  = blk % W;
    const int cx = blk / W;
    const int x  = cx % L;
    const int c  = cx / L;
    const int tid = threadIdx.x;

    // ---- per-thread decode into registers (no LDS table; overlaps staging) ----
    // t[j] = (j/5)*28 + j%5  because j/5 == 5*k0+k1 and j%5 == k2.
    int nbaddr[3][4];   // neighbor LDS index per float4 slot
    int ctr[3];         // CENTER + z0
    int wrapm[3];       // bitmask: slot uses z0+1 (j wrapped past 125)
    #pragma unroll
    for (int i = 0; i < 3; ++i) {
        int e = (i * 256 + tid) * 4;
        unsigned z0 = (unsigned)e / 125u;          // magic mul
        unsigned j0 = (unsigned)e - z0 * 125u;
        int wm = 0;
        #pragma unroll
        for (int u = 0; u < 4; ++u) {
            unsigned ju = j0 + u;
            unsigned zu = z0;
            if (ju >= 125u) { ju -= 125u; zu += 1u; wm |= (1 << u); }
            unsigned q5 = ju / 5u;                 // magic mul
            unsigned r5 = ju - q5 * 5u;
            nbaddr[i][u] = (int)(q5 * ZP + r5 + zu);
        }
        ctr[i] = CENTER + (int)z0;
        wrapm[i] = wm;
    }

    // ---- stage the 5x5x28 zero-padded slab ----
    for (int i = tid; i < NBSZ; i += 256) {
        int kk = i / ZP;
        int zz = i - kk * ZP;
        int gx = x + kk / K - P;
        int gy = y + kk % K - P;
        int gz = zz - P;
        float v = 0.0f;
        if ((unsigned)gx < (unsigned)L && (unsigned)gy < (unsigned)W && (unsigned)gz < (unsigned)H)
            v = q[((c * L + gx) * W + gy) * H + gz];
        s_nb[i] = v;
    }
    __syncthreads();

    float* outp = out + (size_t)blk * PER_BLK;

    // ---- hot loop: 2 center reads (adjacent -> ds_read2) + 4 neighbor reads + store ----
    #pragma unroll
    for (int i = 0; i < 3; ++i) {
        int e4 = i * 256 + tid;
        if (e4 < NV4) {
            float c0 = s_nb[ctr[i]];
            float c1 = s_nb[ctr[i] + 1];
            f32x4 v;
            #pragma unroll
            for (int u = 0; u < 4; ++u) {
                float cc = ((wrapm[i] >> u) & 1) ? c1 : c0;
                float p = cc * s_nb[nbaddr[i][u]];
                v[u] = fmaxf(p, 0.0f);
            }
            *reinterpret_cast<f32x4*>(outp + e4 * 4) = v;
        }
    }
}

extern "C" void kernel_launch(void* const* d_in, const int* in_sizes, int n_in,
                              void* d_out, int out_size, void* d_ws, size_t ws_size,
                              hipStream_t stream) {
    const float* q = (const float*)d_in[0];
    float* out = (float*)d_out;
    const int nblk = C * L * W;   // 18432
    selfcorr_kernel<<<nblk, 256, 0, stream>>>(q, out);
}